// Round 1
// baseline (659.091 us; speedup 1.0000x reference)
//
#include <hip/hip_runtime.h>

#define IN_DIM 128
#define OUT_DIM 128

// ---------------------------------------------------------------------------
// K1: per-node log_map (tangent projection) + gate softmax
// one wave (64 lanes) per node; lane handles dims {2l, 2l+1}
// ---------------------------------------------------------------------------
__global__ __launch_bounds__(256) void k_tangent_gate(
    const float* __restrict__ x, const float* __restrict__ Wg,
    const float* __restrict__ bg, float* __restrict__ xt,
    float* __restrict__ gate, int N) {
  int wid = (blockIdx.x * blockDim.x + threadIdx.x) >> 6;
  int lane = threadIdx.x & 63;
  if (wid >= N) return;

  const float* xr = x + (size_t)wid * 128;
  float2 xv = *(const float2*)(xr + lane * 2);
  xv.x = fminf(fmaxf(xv.x, -10000.f), 10000.f);
  xv.y = fminf(fmaxf(xv.y, -10000.f), 10000.f);

  // pseudo-Riemannian x_sq = -x0^2 + sum_{d>=1} x_d^2
  float p = xv.x * xv.x + xv.y * xv.y;
  if (lane == 0) p -= 2.f * xv.x * xv.x;
  #pragma unroll
  for (int s = 32; s; s >>= 1) p += __shfl_xor(p, s);
  float x0 = __shfl(xv.x, 0);

  // scalar pipeline in fp64 (cancellation near acosh(1+eps))
  double xsq = (double)p;
  double denom = sqrt(fmax(fabs(xsq), 1e-12));
  double cosd = fmax((double)x0 / denom, 1.0 + 1e-6);
  double dist = acosh(cosd);
  double sind = fmax(sqrt(cosd * cosd - 1.0), 1e-12);
  double coef = dist / sind;

  // xt = coef * (x + x0 * e0)  -> dim0 becomes coef*2*x0
  float2 o;
  o.x = (float)(coef * ((lane == 0) ? 2.0 * (double)xv.x : (double)xv.x));
  o.y = (float)(coef * (double)xv.y);
  *(float2*)(xt + (size_t)wid * 128 + lane * 2) = o;

  // gate = softmax(xt @ Wg + bg), Wg is [128,4] row-major
  const float4 w0 = *(const float4*)(Wg + (size_t)(lane * 2) * 4);
  const float4 w1 = *(const float4*)(Wg + (size_t)(lane * 2 + 1) * 4);
  float g0 = o.x * w0.x + o.y * w1.x;
  float g1 = o.x * w0.y + o.y * w1.y;
  float g2 = o.x * w0.z + o.y * w1.z;
  float g3 = o.x * w0.w + o.y * w1.w;
  #pragma unroll
  for (int s = 32; s; s >>= 1) {
    g0 += __shfl_xor(g0, s); g1 += __shfl_xor(g1, s);
    g2 += __shfl_xor(g2, s); g3 += __shfl_xor(g3, s);
  }
  g0 += bg[0]; g1 += bg[1]; g2 += bg[2]; g3 += bg[3];
  float m = fmaxf(fmaxf(g0, g1), fmaxf(g2, g3));
  float e0 = expf(g0 - m), e1 = expf(g1 - m), e2 = expf(g2 - m), e3 = expf(g3 - m);
  float z = e0 + e1 + e2 + e3;
  if (lane == 0)
    *(float4*)(gate + (size_t)wid * 4) = make_float4(e0 / z, e1 / z, e2 / z, e3 / z);
}

// ---------------------------------------------------------------------------
// K2: u_hat[n,d] = sum_k gate[n,k] * (xt[n,:] @ W_per[:, k*128+d] + b_per[k*128+d])
// fp32 tiled GEMM (no fp32 MFMA on CDNA4). BM=64 rows/block, 256 threads,
// thread (ty,tx) computes rows ty*4..+3 x cols tx*8..+7.
// ---------------------------------------------------------------------------
#define GM 64
__global__ __launch_bounds__(256) void k_uhat(
    const float* __restrict__ xt, const float* __restrict__ gate,
    const float* __restrict__ Wp, const float* __restrict__ bp,
    float* __restrict__ uhat, int N) {
  __shared__ float sA[GM][132];   // 132 keeps float4 alignment + bank spread
  __shared__ float sB[32][128];
  int tid = threadIdx.x;
  int m0 = blockIdx.x * GM;

  // load A tile (64 x 128 f32), zero-pad rows >= N
  for (int t = tid; t < GM * 32; t += 256) {
    int r = t >> 5, c4 = t & 31;
    float4 v = make_float4(0.f, 0.f, 0.f, 0.f);
    if (m0 + r < N) v = *(const float4*)(xt + (size_t)(m0 + r) * 128 + c4 * 4);
    *(float4*)(&sA[r][c4 * 4]) = v;
  }

  int tx = tid & 15, ty = tid >> 4;
  float acc[4][8];
  #pragma unroll
  for (int a = 0; a < 4; a++)
    #pragma unroll
    for (int b = 0; b < 8; b++) acc[a][b] = 0.f;

  for (int k = 0; k < 4; ++k) {            // 4 perspectives
    float tmp[4][8];
    #pragma unroll
    for (int a = 0; a < 4; a++)
      #pragma unroll
      for (int b = 0; b < 8; b++) tmp[a][b] = 0.f;

    for (int c = 0; c < 4; ++c) {          // K chunks of 32
      __syncthreads();
      for (int t = tid; t < 32 * 32; t += 256) {
        int r = t >> 5, c4 = t & 31;
        float4 v = *(const float4*)(Wp + (size_t)(c * 32 + r) * 512 + k * 128 + c4 * 4);
        *(float4*)(&sB[r][c4 * 4]) = v;
      }
      __syncthreads();
      #pragma unroll
      for (int i4 = 0; i4 < 8; ++i4) {
        float4 a4[4];
        #pragma unroll
        for (int mm = 0; mm < 4; mm++)
          a4[mm] = *(const float4*)(&sA[ty * 4 + mm][c * 32 + i4 * 4]);
        #pragma unroll
        for (int ii = 0; ii < 4; ++ii) {
          float4 blo = *(const float4*)(&sB[i4 * 4 + ii][tx * 8]);
          float4 bhi = *(const float4*)(&sB[i4 * 4 + ii][tx * 8 + 4]);
          float bb[8] = {blo.x, blo.y, blo.z, blo.w, bhi.x, bhi.y, bhi.z, bhi.w};
          #pragma unroll
          for (int mm = 0; mm < 4; mm++) {
            float av = (ii == 0) ? a4[mm].x : (ii == 1) ? a4[mm].y
                      : (ii == 2) ? a4[mm].z : a4[mm].w;
            #pragma unroll
            for (int j = 0; j < 8; j++) tmp[mm][j] = fmaf(av, bb[j], tmp[mm][j]);
          }
        }
      }
    }
    // gate-weighted combine (+ per-perspective bias b_per)
    #pragma unroll
    for (int mm = 0; mm < 4; mm++) {
      int r = m0 + ty * 4 + mm;
      float g = (r < N) ? gate[(size_t)r * 4 + k] : 0.f;
      #pragma unroll
      for (int j = 0; j < 8; j++)
        acc[mm][j] += g * (tmp[mm][j] + bp[k * 128 + tx * 8 + j]);
    }
  }
  #pragma unroll
  for (int mm = 0; mm < 4; mm++) {
    int r = m0 + ty * 4 + mm;
    if (r < N) {
      *(float4*)(uhat + (size_t)r * 128 + tx * 8) =
          make_float4(acc[mm][0], acc[mm][1], acc[mm][2], acc[mm][3]);
      *(float4*)(uhat + (size_t)r * 128 + tx * 8 + 4) =
          make_float4(acc[mm][4], acc[mm][5], acc[mm][6], acc[mm][7]);
    }
  }
}

// ---------------------------------------------------------------------------
// CSR-by-col construction
// ---------------------------------------------------------------------------
__global__ void k_hist(const int* __restrict__ col, int* __restrict__ deg, int E) {
  int e = blockIdx.x * blockDim.x + threadIdx.x;
  if (e < E) atomicAdd(&deg[col[e]], 1);
}

__global__ void k_scan(const int* __restrict__ deg, int* __restrict__ off,
                       int* __restrict__ cur, int N) {
  __shared__ int buf[256];
  __shared__ int carry;
  int tid = threadIdx.x;
  if (tid == 0) carry = 0;
  __syncthreads();
  for (int base = 0; base < N; base += 256) {
    int i = base + tid;
    int v = (i < N) ? deg[i] : 0;
    buf[tid] = v;
    __syncthreads();
    #pragma unroll
    for (int s = 1; s < 256; s <<= 1) {
      int t = (tid >= s) ? buf[tid - s] : 0;
      __syncthreads();
      buf[tid] += t;
      __syncthreads();
    }
    int excl = buf[tid] - v + carry;
    if (i < N) { off[i] = excl; cur[i] = excl; }
    __syncthreads();
    if (tid == 255) carry += buf[255];
    __syncthreads();
  }
  if (tid == 0) off[N] = carry;
}

__global__ void k_scatter(const int* __restrict__ row, const int* __restrict__ col,
                          int* __restrict__ cur, int* __restrict__ csr_row, int E) {
  int e = blockIdx.x * blockDim.x + threadIdx.x;
  if (e < E) {
    int p = atomicAdd(&cur[col[e]], 1);
    csr_row[p] = row[e];
  }
}

// ---------------------------------------------------------------------------
// K6: fused 3-iteration dynamic routing + squash + exp_map.
// One wave per destination node. Per-edge logits b in LDS (fallback to global
// scratch for pathological degree). Lane handles dims {2l, 2l+1}.
// ---------------------------------------------------------------------------
#define MAXB 1024
__global__ __launch_bounds__(64) void k_route(
    const float* __restrict__ uhat, const float* __restrict__ bias,
    const int* __restrict__ csr_off, const int* __restrict__ csr_row,
    float* __restrict__ bg_ws, float* __restrict__ out, int N) {
  __shared__ float bl[MAXB];
  __shared__ int rl[MAXB];
  int j = blockIdx.x;
  int lane = threadIdx.x;
  int o0 = csr_off[j];
  int deg = csr_off[j + 1] - o0;
  bool big = deg > MAXB;
  float* b = big ? (bg_ws + o0) : bl;

  for (int i = lane; i < deg; i += 64) {
    int r = csr_row[o0 + i];
    if (!big) rl[i] = r;
    b[i] = 0.f;
  }
  if (big) __threadfence();
  __syncthreads();

  int d0 = lane * 2;
  float2 bia = *(const float2*)(bias + d0);
  float s0 = 0.f, s1 = 0.f;

  for (int r = 0; r < 3; ++r) {
    // segment softmax over this node's edges
    float mx = -3.4e38f;
    for (int i = lane; i < deg; i += 64) mx = fmaxf(mx, b[i]);
    #pragma unroll
    for (int s = 32; s; s >>= 1) mx = fmaxf(mx, __shfl_xor(mx, s));
    float z = 0.f;
    for (int i = lane; i < deg; i += 64) z += expf(b[i] - mx);
    #pragma unroll
    for (int s = 32; s; s >>= 1) z += __shfl_xor(z, s);
    float invz = 1.f / z;

    // s_j = sum_i c_i * u_hat[row_i]  (+ bias, since sum c_i = 1)
    s0 = 0.f; s1 = 0.f;
    for (int i = 0; i < deg; ++i) {
      float c = expf(b[i] - mx) * invz;
      int rr = big ? csr_row[o0 + i] : rl[i];
      float2 u = *(const float2*)(uhat + (size_t)rr * 128 + d0);
      s0 = fmaf(c, u.x, s0);
      s1 = fmaf(c, u.y, s1);
    }
    if (deg > 0) { s0 += bia.x; s1 += bia.y; }

    // squash
    float ns = s0 * s0 + s1 * s1;
    #pragma unroll
    for (int s = 32; s; s >>= 1) ns += __shfl_xor(ns, s);
    float scale = (ns / (1.f + ns)) / sqrtf(ns + 1e-9f);
    s0 *= scale; s1 *= scale;

    // b_ij += dot(s_j, u_hat[row_i])  (u_hat, NOT u_b)
    if (r < 2) {
      for (int i = 0; i < deg; ++i) {
        int rr = big ? csr_row[o0 + i] : rl[i];
        float2 u = *(const float2*)(uhat + (size_t)rr * 128 + d0);
        float pp = s0 * u.x + s1 * u.y;
        #pragma unroll
        for (int s = 32; s; s >>= 1) pp += __shfl_xor(pp, s);
        if (lane == 0) b[i] += pp;
      }
      if (big) __threadfence();
      __syncthreads();
    }
  }

  // exp_map(s, ref): pseudo-inner, fp64 scalars
  float pn = s0 * s0 + s1 * s1;
  if (lane == 0) pn -= 2.f * s0 * s0;
  #pragma unroll
  for (int s = 32; s; s >>= 1) pn += __shfl_xor(pn, s);
  double vn = fmin(sqrt(fabs((double)pn) + 1e-12), 10.0);
  double sh = sinh(vn) / vn;
  float ov0 = (float)(sh * (double)s0 + ((lane == 0) ? cosh(vn) : 0.0));
  float ov1 = (float)(sh * (double)s1);
  *(float2*)(out + (size_t)j * 128 + d0) = make_float2(ov0, ov1);
}

// ---------------------------------------------------------------------------
extern "C" void kernel_launch(void* const* d_in, const int* in_sizes, int n_in,
                              void* d_out, int out_size, void* d_ws, size_t ws_size,
                              hipStream_t stream) {
  const float* x    = (const float*)d_in[0];
  const int*   ei   = (const int*)d_in[1];
  const float* Wp   = (const float*)d_in[2];
  const float* bp   = (const float*)d_in[3];
  const float* Wg   = (const float*)d_in[4];
  const float* bg   = (const float*)d_in[5];
  const float* bias = (const float*)d_in[6];
  float* out = (float*)d_out;

  int N = in_sizes[0] / 128;
  int E = in_sizes[1] / 2;
  const int* row = ei;
  const int* col = ei + E;

  // workspace layout (all 16B-aligned given sizes)
  float* xt   = (float*)d_ws;
  float* uh   = xt + (size_t)N * 128;
  float* gate = uh + (size_t)N * 128;
  float* bws  = gate + (size_t)N * 4;
  int* deg    = (int*)(bws + E);
  int* off    = deg + N;
  int* cur    = off + N + 1;
  int* csr_row = cur + N;

  hipMemsetAsync(deg, 0, (size_t)N * sizeof(int), stream);
  k_tangent_gate<<<(N + 3) / 4, 256, 0, stream>>>(x, Wg, bg, xt, gate, N);
  k_uhat<<<(N + GM - 1) / GM, 256, 0, stream>>>(xt, gate, Wp, bp, uh, N);
  k_hist<<<(E + 255) / 256, 256, 0, stream>>>(col, deg, E);
  k_scan<<<1, 256, 0, stream>>>(deg, off, cur, N);
  k_scatter<<<(E + 255) / 256, 256, 0, stream>>>(row, col, cur, csr_row, E);
  k_route<<<N, 64, 0, stream>>>(uh, bias, off, csr_row, bws, out, N);
}

// Round 2
// 435.741 us; speedup vs baseline: 1.5126x; 1.5126x over previous
//
#include <hip/hip_runtime.h>

#define IN_DIM 128
#define OUT_DIM 128

// ---------------------------------------------------------------------------
// K1: per-node log_map (tangent projection) + gate softmax
// one wave (64 lanes) per node; lane handles dims {2l, 2l+1}
// ---------------------------------------------------------------------------
__global__ __launch_bounds__(256) void k_tangent_gate(
    const float* __restrict__ x, const float* __restrict__ Wg,
    const float* __restrict__ bg, float* __restrict__ xt,
    float* __restrict__ gate, int N) {
  int wid = (blockIdx.x * blockDim.x + threadIdx.x) >> 6;
  int lane = threadIdx.x & 63;
  if (wid >= N) return;

  const float* xr = x + (size_t)wid * 128;
  float2 xv = *(const float2*)(xr + lane * 2);
  xv.x = fminf(fmaxf(xv.x, -10000.f), 10000.f);
  xv.y = fminf(fmaxf(xv.y, -10000.f), 10000.f);

  // pseudo-Riemannian x_sq = -x0^2 + sum_{d>=1} x_d^2
  float p = xv.x * xv.x + xv.y * xv.y;
  if (lane == 0) p -= 2.f * xv.x * xv.x;
  #pragma unroll
  for (int s = 32; s; s >>= 1) p += __shfl_xor(p, s);
  float x0 = __shfl(xv.x, 0);

  // scalar pipeline in fp64 (cancellation near acosh(1+eps))
  double xsq = (double)p;
  double denom = sqrt(fmax(fabs(xsq), 1e-12));
  double cosd = fmax((double)x0 / denom, 1.0 + 1e-6);
  double dist = acosh(cosd);
  double sind = fmax(sqrt(cosd * cosd - 1.0), 1e-12);
  double coef = dist / sind;

  // xt = coef * (x + x0 * e0)  -> dim0 becomes coef*2*x0
  float2 o;
  o.x = (float)(coef * ((lane == 0) ? 2.0 * (double)xv.x : (double)xv.x));
  o.y = (float)(coef * (double)xv.y);
  *(float2*)(xt + (size_t)wid * 128 + lane * 2) = o;

  // gate = softmax(xt @ Wg + bg), Wg is [128,4] row-major
  const float4 w0 = *(const float4*)(Wg + (size_t)(lane * 2) * 4);
  const float4 w1 = *(const float4*)(Wg + (size_t)(lane * 2 + 1) * 4);
  float g0 = o.x * w0.x + o.y * w1.x;
  float g1 = o.x * w0.y + o.y * w1.y;
  float g2 = o.x * w0.z + o.y * w1.z;
  float g3 = o.x * w0.w + o.y * w1.w;
  #pragma unroll
  for (int s = 32; s; s >>= 1) {
    g0 += __shfl_xor(g0, s); g1 += __shfl_xor(g1, s);
    g2 += __shfl_xor(g2, s); g3 += __shfl_xor(g3, s);
  }
  g0 += bg[0]; g1 += bg[1]; g2 += bg[2]; g3 += bg[3];
  float m = fmaxf(fmaxf(g0, g1), fmaxf(g2, g3));
  float e0 = expf(g0 - m), e1 = expf(g1 - m), e2 = expf(g2 - m), e3 = expf(g3 - m);
  float z = e0 + e1 + e2 + e3;
  if (lane == 0)
    *(float4*)(gate + (size_t)wid * 4) = make_float4(e0 / z, e1 / z, e2 / z, e3 / z);
}

// ---------------------------------------------------------------------------
// K2: u_hat[n,d] = sum_k gate[n,k] * (xt[n,:] @ W_per[:, k*128+d] + b_per[k*128+d])
// fp32 tiled GEMM (no fp32 MFMA on CDNA4).
// ---------------------------------------------------------------------------
#define GM 64
__global__ __launch_bounds__(256) void k_uhat(
    const float* __restrict__ xt, const float* __restrict__ gate,
    const float* __restrict__ Wp, const float* __restrict__ bp,
    float* __restrict__ uhat, int N) {
  __shared__ float sA[GM][132];
  __shared__ float sB[32][128];
  int tid = threadIdx.x;
  int m0 = blockIdx.x * GM;

  for (int t = tid; t < GM * 32; t += 256) {
    int r = t >> 5, c4 = t & 31;
    float4 v = make_float4(0.f, 0.f, 0.f, 0.f);
    if (m0 + r < N) v = *(const float4*)(xt + (size_t)(m0 + r) * 128 + c4 * 4);
    *(float4*)(&sA[r][c4 * 4]) = v;
  }

  int tx = tid & 15, ty = tid >> 4;
  float acc[4][8];
  #pragma unroll
  for (int a = 0; a < 4; a++)
    #pragma unroll
    for (int b = 0; b < 8; b++) acc[a][b] = 0.f;

  for (int k = 0; k < 4; ++k) {
    float tmp[4][8];
    #pragma unroll
    for (int a = 0; a < 4; a++)
      #pragma unroll
      for (int b = 0; b < 8; b++) tmp[a][b] = 0.f;

    for (int c = 0; c < 4; ++c) {
      __syncthreads();
      for (int t = tid; t < 32 * 32; t += 256) {
        int r = t >> 5, c4 = t & 31;
        float4 v = *(const float4*)(Wp + (size_t)(c * 32 + r) * 512 + k * 128 + c4 * 4);
        *(float4*)(&sB[r][c4 * 4]) = v;
      }
      __syncthreads();
      #pragma unroll
      for (int i4 = 0; i4 < 8; ++i4) {
        float4 a4[4];
        #pragma unroll
        for (int mm = 0; mm < 4; mm++)
          a4[mm] = *(const float4*)(&sA[ty * 4 + mm][c * 32 + i4 * 4]);
        #pragma unroll
        for (int ii = 0; ii < 4; ++ii) {
          float4 blo = *(const float4*)(&sB[i4 * 4 + ii][tx * 8]);
          float4 bhi = *(const float4*)(&sB[i4 * 4 + ii][tx * 8 + 4]);
          float bb[8] = {blo.x, blo.y, blo.z, blo.w, bhi.x, bhi.y, bhi.z, bhi.w};
          #pragma unroll
          for (int mm = 0; mm < 4; mm++) {
            float av = (ii == 0) ? a4[mm].x : (ii == 1) ? a4[mm].y
                      : (ii == 2) ? a4[mm].z : a4[mm].w;
            #pragma unroll
            for (int j = 0; j < 8; j++) tmp[mm][j] = fmaf(av, bb[j], tmp[mm][j]);
          }
        }
      }
    }
    #pragma unroll
    for (int mm = 0; mm < 4; mm++) {
      int r = m0 + ty * 4 + mm;
      float g = (r < N) ? gate[(size_t)r * 4 + k] : 0.f;
      #pragma unroll
      for (int j = 0; j < 8; j++)
        acc[mm][j] += g * (tmp[mm][j] + bp[k * 128 + tx * 8 + j]);
    }
  }
  #pragma unroll
  for (int mm = 0; mm < 4; mm++) {
    int r = m0 + ty * 4 + mm;
    if (r < N) {
      *(float4*)(uhat + (size_t)r * 128 + tx * 8) =
          make_float4(acc[mm][0], acc[mm][1], acc[mm][2], acc[mm][3]);
      *(float4*)(uhat + (size_t)r * 128 + tx * 8 + 4) =
          make_float4(acc[mm][4], acc[mm][5], acc[mm][6], acc[mm][7]);
    }
  }
}

// ---------------------------------------------------------------------------
// CSR-by-col construction: histogram + hierarchical scan + scatter
// ---------------------------------------------------------------------------
__global__ void k_hist(const int* __restrict__ col, int* __restrict__ deg, int E) {
  int e = blockIdx.x * blockDim.x + threadIdx.x;
  if (e < E) atomicAdd(&deg[col[e]], 1);
}

#define SCH 1024
__global__ __launch_bounds__(256) void k_bsum(const int* __restrict__ deg,
                                              int* __restrict__ bsum, int N) {
  __shared__ int ws[4];
  int tid = threadIdx.x;
  int base = blockIdx.x * SCH;
  int v = 0;
  #pragma unroll
  for (int k = 0; k < 4; k++) {
    int i = base + k * 256 + tid;
    if (i < N) v += deg[i];
  }
  #pragma unroll
  for (int s = 32; s; s >>= 1) v += __shfl_xor(v, s);
  if ((tid & 63) == 0) ws[tid >> 6] = v;
  __syncthreads();
  if (tid == 0) bsum[blockIdx.x] = ws[0] + ws[1] + ws[2] + ws[3];
}

__global__ __launch_bounds__(64) void k_bscan(const int* __restrict__ bsum,
                                              int* __restrict__ boff,
                                              int* __restrict__ off, int NB, int N) {
  int lane = threadIdx.x;
  int carry = 0;
  for (int base = 0; base < NB; base += 64) {
    int i = base + lane;
    int v = (i < NB) ? bsum[i] : 0;
    int sc = v;
    #pragma unroll
    for (int s = 1; s < 64; s <<= 1) {
      int t = __shfl_up(sc, s);
      if (lane >= s) sc += t;
    }
    if (i < NB) boff[i] = carry + sc - v;
    carry += __shfl(sc, 63);
  }
  if (lane == 0) off[N] = carry;
}

__global__ __launch_bounds__(256) void k_scan2(const int* __restrict__ deg,
                                               const int* __restrict__ boff,
                                               int* __restrict__ off,
                                               int* __restrict__ cur, int N) {
  __shared__ int wtot[4];
  int tid = threadIdx.x;
  int lane = tid & 63;
  int base = blockIdx.x * SCH + tid * 4;
  int v[4];
  #pragma unroll
  for (int k = 0; k < 4; k++) v[k] = (base + k < N) ? deg[base + k] : 0;
  int tsum = v[0] + v[1] + v[2] + v[3];
  int sc = tsum;
  #pragma unroll
  for (int s = 1; s < 64; s <<= 1) {
    int t = __shfl_up(sc, s);
    if (lane >= s) sc += t;
  }
  if (lane == 63) wtot[tid >> 6] = sc;
  __syncthreads();
  int w = tid >> 6;
  int woff = 0;
  if (w > 0) woff += wtot[0];
  if (w > 1) woff += wtot[1];
  if (w > 2) woff += wtot[2];
  int pre = boff[blockIdx.x] + woff + sc - tsum;
  #pragma unroll
  for (int k = 0; k < 4; k++) {
    int i = base + k;
    if (i < N) { off[i] = pre; cur[i] = pre; }
    pre += v[k];
  }
}

__global__ void k_scatter(const int* __restrict__ row, const int* __restrict__ col,
                          int* __restrict__ cur, int* __restrict__ csr_row, int E) {
  int e = blockIdx.x * blockDim.x + threadIdx.x;
  if (e < E) {
    int p = atomicAdd(&cur[col[e]], 1);
    csr_row[p] = row[e];
  }
}

// ---------------------------------------------------------------------------
// K6: fused 3-iteration dynamic routing + squash + exp_map.
// One wave per destination node. u rows staged ONCE in LDS (deg<=CAP),
// softmax without max-shift and without cross-lane reductions (redundant z),
// b-update dots batched 8-wide for independent butterfly chains.
// Global-memory fallback path for deg>CAP (correct, rare).
// ---------------------------------------------------------------------------
#define CAP 32
__global__ __launch_bounds__(64) void k_route(
    const float* __restrict__ uhat, const float* __restrict__ bias,
    const int* __restrict__ csr_off, const int* __restrict__ csr_row,
    float* __restrict__ bg_ws, float* __restrict__ out, int N) {
  __shared__ float ulds[CAP][130];
  __shared__ float bl[CAP];
  int j = blockIdx.x;
  int lane = threadIdx.x;
  int o0 = csr_off[j];
  int deg = csr_off[j + 1] - o0;
  int d0 = lane * 2;

  if (deg == 0) {
    // empty segment: squash(0)=0, exp_map(0) = pole = e0
    *(float2*)(out + (size_t)j * 128 + d0) =
        make_float2((lane == 0) ? 1.f : 0.f, 0.f);
    return;
  }

  float2 bia = *(const float2*)(bias + d0);
  float s0 = 0.f, s1 = 0.f;

  if (deg <= CAP) {
    // ---- stage u rows into LDS (indices fetched lane-parallel) ----
    int myrow = (lane < deg) ? csr_row[o0 + lane] : 0;
    for (int i = 0; i < deg; ++i) {
      int rr = __shfl(myrow, i);
      float2 u = *(const float2*)(uhat + (size_t)rr * 128 + d0);
      *(float2*)(&ulds[i][d0]) = u;
    }
    if (lane < CAP) bl[lane] = 0.f;
    __syncthreads();

    for (int r = 0; r < 3; ++r) {
      // softmax-weighted sum; z accumulated redundantly in every lane
      float z = 0.f, a0 = 0.f, a1 = 0.f;
      for (int i = 0; i < deg; ++i) {
        float e = __expf(bl[i]);
        float2 u = *(const float2*)(&ulds[i][d0]);
        z += e;
        a0 = fmaf(e, u.x, a0);
        a1 = fmaf(e, u.y, a1);
      }
      float invz = 1.f / z;
      s0 = a0 * invz + bia.x;
      s1 = a1 * invz + bia.y;

      // squash
      float ns = s0 * s0 + s1 * s1;
      #pragma unroll
      for (int s = 32; s; s >>= 1) ns += __shfl_xor(ns, s);
      float scale = (ns / (1.f + ns)) * rsqrtf(ns + 1e-9f);
      s0 *= scale; s1 *= scale;

      // b_i += dot(s, u_i): 8 independent butterfly chains per batch
      if (r < 2) {
        for (int i0 = 0; i0 < deg; i0 += 8) {
          float p[8];
          #pragma unroll
          for (int k = 0; k < 8; k++) {
            int i = i0 + k;
            float2 u = (i < deg) ? *(const float2*)(&ulds[i][d0])
                                 : make_float2(0.f, 0.f);
            p[k] = s0 * u.x + s1 * u.y;
          }
          #pragma unroll
          for (int k = 0; k < 8; k++)
            #pragma unroll
            for (int s = 32; s; s >>= 1) p[k] += __shfl_xor(p[k], s);
          float pv = p[0];
          #pragma unroll
          for (int k = 1; k < 8; k++) pv = (lane == k) ? p[k] : pv;
          if (lane < 8 && i0 + lane < deg) bl[i0 + lane] += pv;
        }
        __syncthreads();
      }
    }
  } else {
    // ---- fallback: global-memory path (rare pathological degree) ----
    float* b = bg_ws + o0;
    for (int i = lane; i < deg; i += 64) b[i] = 0.f;
    __threadfence();
    __syncthreads();

    for (int r = 0; r < 3; ++r) {
      float mx = -3.4e38f;
      for (int i = lane; i < deg; i += 64) mx = fmaxf(mx, b[i]);
      #pragma unroll
      for (int s = 32; s; s >>= 1) mx = fmaxf(mx, __shfl_xor(mx, s));
      float z = 0.f;
      for (int i = lane; i < deg; i += 64) z += expf(b[i] - mx);
      #pragma unroll
      for (int s = 32; s; s >>= 1) z += __shfl_xor(z, s);
      float invz = 1.f / z;

      s0 = 0.f; s1 = 0.f;
      for (int i = 0; i < deg; ++i) {
        float c = expf(b[i] - mx) * invz;
        int rr = csr_row[o0 + i];
        float2 u = *(const float2*)(uhat + (size_t)rr * 128 + d0);
        s0 = fmaf(c, u.x, s0);
        s1 = fmaf(c, u.y, s1);
      }
      s0 += bia.x; s1 += bia.y;

      float ns = s0 * s0 + s1 * s1;
      #pragma unroll
      for (int s = 32; s; s >>= 1) ns += __shfl_xor(ns, s);
      float scale = (ns / (1.f + ns)) * rsqrtf(ns + 1e-9f);
      s0 *= scale; s1 *= scale;

      if (r < 2) {
        for (int i = 0; i < deg; ++i) {
          int rr = csr_row[o0 + i];
          float2 u = *(const float2*)(uhat + (size_t)rr * 128 + d0);
          float pp = s0 * u.x + s1 * u.y;
          #pragma unroll
          for (int s = 32; s; s >>= 1) pp += __shfl_xor(pp, s);
          if (lane == 0) b[i] += pp;
        }
        __threadfence();
        __syncthreads();
      }
    }
  }

  // exp_map(s, ref): fp32
  float pn = s0 * s0 + s1 * s1;
  if (lane == 0) pn -= 2.f * s0 * s0;
  #pragma unroll
  for (int s = 32; s; s >>= 1) pn += __shfl_xor(pn, s);
  float vn = fminf(sqrtf(fabsf(pn) + 1e-12f), 10.f);
  float sh = sinhf(vn) / vn;
  float ov0 = sh * s0 + ((lane == 0) ? coshf(vn) : 0.f);
  float ov1 = sh * s1;
  *(float2*)(out + (size_t)j * 128 + d0) = make_float2(ov0, ov1);
}

// ---------------------------------------------------------------------------
extern "C" void kernel_launch(void* const* d_in, const int* in_sizes, int n_in,
                              void* d_out, int out_size, void* d_ws, size_t ws_size,
                              hipStream_t stream) {
  const float* x    = (const float*)d_in[0];
  const int*   ei   = (const int*)d_in[1];
  const float* Wp   = (const float*)d_in[2];
  const float* bp   = (const float*)d_in[3];
  const float* Wg   = (const float*)d_in[4];
  const float* bg   = (const float*)d_in[5];
  const float* bias = (const float*)d_in[6];
  float* out = (float*)d_out;

  int N = in_sizes[0] / 128;
  int E = in_sizes[1] / 2;
  const int* row = ei;
  const int* col = ei + E;
  int NB = (N + SCH - 1) / SCH;

  float* xt   = (float*)d_ws;
  float* uh   = xt + (size_t)N * 128;
  float* gate = uh + (size_t)N * 128;
  float* bws  = gate + (size_t)N * 4;
  int* deg    = (int*)(bws + E);
  int* off    = deg + N;
  int* cur    = off + N + 1;
  int* csr_row = cur + N;
  int* bsum   = csr_row + E;
  int* boff   = bsum + NB;

  hipMemsetAsync(deg, 0, (size_t)N * sizeof(int), stream);
  k_tangent_gate<<<(N + 3) / 4, 256, 0, stream>>>(x, Wg, bg, xt, gate, N);
  k_uhat<<<(N + GM - 1) / GM, 256, 0, stream>>>(xt, gate, Wp, bp, uh, N);
  k_hist<<<(E + 255) / 256, 256, 0, stream>>>(col, deg, E);
  k_bsum<<<NB, 256, 0, stream>>>(deg, bsum, N);
  k_bscan<<<1, 64, 0, stream>>>(bsum, boff, off, NB, N);
  k_scan2<<<NB, 256, 0, stream>>>(deg, boff, off, cur, N);
  k_scatter<<<(E + 255) / 256, 256, 0, stream>>>(row, col, cur, csr_row, E);
  k_route<<<N, 64, 0, stream>>>(uh, bias, off, csr_row, bws, out, N);
}

// Round 3
// 261.683 us; speedup vs baseline: 2.5187x; 1.6652x over previous
//
#include <hip/hip_runtime.h>
#include <hip/hip_fp16.h>
#include <hip/hip_bf16.h>

typedef short bf16x8 __attribute__((ext_vector_type(8)));
typedef float f32x4 __attribute__((ext_vector_type(4)));

// ---------------------------------------------------------------------------
// K1: per-node log_map (tangent projection, bf16 output) + gate softmax
// one wave per node; lane handles dims {2l, 2l+1}
// ---------------------------------------------------------------------------
__global__ __launch_bounds__(256) void k_tangent_gate(
    const float* __restrict__ x, const float* __restrict__ Wg,
    const float* __restrict__ bg, __hip_bfloat16* __restrict__ xtb,
    float* __restrict__ gate, int N) {
  int wid = (blockIdx.x * blockDim.x + threadIdx.x) >> 6;
  int lane = threadIdx.x & 63;
  if (wid >= N) return;

  const float* xr = x + (size_t)wid * 128;
  float2 xv = *(const float2*)(xr + lane * 2);
  xv.x = fminf(fmaxf(xv.x, -10000.f), 10000.f);
  xv.y = fminf(fmaxf(xv.y, -10000.f), 10000.f);

  // pseudo-Riemannian x_sq = -x0^2 + sum_{d>=1} x_d^2
  float p = xv.x * xv.x + xv.y * xv.y;
  if (lane == 0) p -= 2.f * xv.x * xv.x;
  #pragma unroll
  for (int s = 32; s; s >>= 1) p += __shfl_xor(p, s);
  float x0 = __shfl(xv.x, 0);

  // scalar pipeline in fp64 (cancellation near acosh(1+eps))
  double xsq = (double)p;
  double denom = sqrt(fmax(fabs(xsq), 1e-12));
  double cosd = fmax((double)x0 / denom, 1.0 + 1e-6);
  double dist = acosh(cosd);
  double sind = fmax(sqrt(cosd * cosd - 1.0), 1e-12);
  double coef = dist / sind;

  float2 o;
  o.x = (float)(coef * ((lane == 0) ? 2.0 * (double)xv.x : (double)xv.x));
  o.y = (float)(coef * (double)xv.y);
  __hip_bfloat162 hb = __float22bfloat162_rn(make_float2(o.x, o.y));
  *(__hip_bfloat162*)(xtb + (size_t)wid * 128 + lane * 2) = hb;

  // gate = softmax(o @ Wg + bg)
  const float4 w0 = *(const float4*)(Wg + (size_t)(lane * 2) * 4);
  const float4 w1 = *(const float4*)(Wg + (size_t)(lane * 2 + 1) * 4);
  float g0 = o.x * w0.x + o.y * w1.x;
  float g1 = o.x * w0.y + o.y * w1.y;
  float g2 = o.x * w0.z + o.y * w1.z;
  float g3 = o.x * w0.w + o.y * w1.w;
  #pragma unroll
  for (int s = 32; s; s >>= 1) {
    g0 += __shfl_xor(g0, s); g1 += __shfl_xor(g1, s);
    g2 += __shfl_xor(g2, s); g3 += __shfl_xor(g3, s);
  }
  g0 += bg[0]; g1 += bg[1]; g2 += bg[2]; g3 += bg[3];
  float m = fmaxf(fmaxf(g0, g1), fmaxf(g2, g3));
  float e0 = expf(g0 - m), e1 = expf(g1 - m), e2 = expf(g2 - m), e3 = expf(g3 - m);
  float z = e0 + e1 + e2 + e3;
  if (lane == 0)
    *(float4*)(gate + (size_t)wid * 4) = make_float4(e0 / z, e1 / z, e2 / z, e3 / z);
}

// ---------------------------------------------------------------------------
// K1b: transpose W_per [128,512] f32 -> Wt [512,128] bf16 (K-contiguous rows)
// ---------------------------------------------------------------------------
__global__ __launch_bounds__(256) void k_wt(const float* __restrict__ Wp,
                                            __hip_bfloat16* __restrict__ Wt) {
  int idx = blockIdx.x * 256 + threadIdx.x;   // 65536 total
  int n = idx >> 7, k = idx & 127;
  Wt[idx] = __float2bfloat16(Wp[(size_t)k * 512 + n]);
}

// ---------------------------------------------------------------------------
// K2: u_hat via bf16 MFMA.  u[n,d] = sum_p gate[n,p]*(xt[n,:]@W[:,p,d]+bp[p,d])
// 64 rows/block, 4 waves; wave w owns rows [w*16,w*16+16) x all 128 cols.
// A frag: lane&15=row, (lane>>4)*8=k;  B frag: lane&15=col, (lane>>4)*8=k.
// C/D: col=lane&15, row=(lane>>4)*4+reg  [verified layout].
// Output f16.
// ---------------------------------------------------------------------------
#define BM 64
__global__ __launch_bounds__(256) void k_uhat_mfma(
    const short* __restrict__ xtb, const float* __restrict__ gate,
    const short* __restrict__ Wt, const float* __restrict__ bp,
    __half* __restrict__ uh, int N) {
  __shared__ short sA[BM][136];
  __shared__ short sB[128][136];
  int tid = threadIdx.x;
  int lane = tid & 63;
  int w = tid >> 6;
  int m0 = blockIdx.x * BM;

  // stage A (64 x 128 bf16)
  #pragma unroll
  for (int it = 0; it < 4; ++it) {
    int idx = it * 256 + tid;
    int r = idx >> 4, c = idx & 15;
    int4 v = make_int4(0, 0, 0, 0);
    if (m0 + r < N) v = *(const int4*)(xtb + (((size_t)(m0 + r)) << 7) + c * 8);
    *(int4*)(&sA[r][c * 8]) = v;
  }

  int mr = w * 16;
  int ri = lane & 15;
  int kg = lane >> 4;
  int rbase = m0 + mr + kg * 4;

  float fin[8][4];
  #pragma unroll
  for (int nt = 0; nt < 8; ++nt)
    #pragma unroll
    for (int q = 0; q < 4; ++q) fin[nt][q] = 0.f;

  for (int p = 0; p < 4; ++p) {
    __syncthreads();
    #pragma unroll
    for (int it = 0; it < 8; ++it) {
      int idx = it * 256 + tid;
      int r = idx >> 4, c = idx & 15;
      int4 v = *(const int4*)(Wt + (((size_t)p * 128 + r) << 7) + c * 8);
      *(int4*)(&sB[r][c * 8]) = v;
    }
    __syncthreads();

    bf16x8 af[4];
    #pragma unroll
    for (int ks = 0; ks < 4; ++ks)
      af[ks] = *(const bf16x8*)(&sA[mr + ri][ks * 32 + kg * 8]);

    #pragma unroll
    for (int nt = 0; nt < 8; ++nt) {
      f32x4 acc = {0.f, 0.f, 0.f, 0.f};
      #pragma unroll
      for (int ks = 0; ks < 4; ++ks) {
        bf16x8 bf = *(const bf16x8*)(&sB[nt * 16 + ri][ks * 32 + kg * 8]);
        acc = __builtin_amdgcn_mfma_f32_16x16x32_bf16(af[ks], bf, acc, 0, 0, 0);
      }
      float bpv = bp[p * 128 + nt * 16 + ri];
      #pragma unroll
      for (int q = 0; q < 4; ++q) {
        int rm = rbase + q;
        float g = (rm < N) ? gate[(size_t)rm * 4 + p] : 0.f;
        fin[nt][q] += g * (acc[q] + bpv);
      }
    }
  }
  #pragma unroll
  for (int nt = 0; nt < 8; ++nt) {
    int cn = nt * 16 + ri;
    #pragma unroll
    for (int q = 0; q < 4; ++q) {
      int rm = rbase + q;
      if (rm < N) uh[(size_t)rm * 128 + cn] = __float2half_rn(fin[nt][q]);
    }
  }
}

// ---------------------------------------------------------------------------
// CSR-by-col: histogram + hierarchical scan + scatter
// ---------------------------------------------------------------------------
__global__ void k_hist(const int* __restrict__ col, int* __restrict__ deg, int E) {
  int e = blockIdx.x * blockDim.x + threadIdx.x;
  if (e < E) atomicAdd(&deg[col[e]], 1);
}

#define SCH 1024
__global__ __launch_bounds__(256) void k_bsum(const int* __restrict__ deg,
                                              int* __restrict__ bsum, int N) {
  __shared__ int ws[4];
  int tid = threadIdx.x;
  int base = blockIdx.x * SCH;
  int v = 0;
  #pragma unroll
  for (int k = 0; k < 4; k++) {
    int i = base + k * 256 + tid;
    if (i < N) v += deg[i];
  }
  #pragma unroll
  for (int s = 32; s; s >>= 1) v += __shfl_xor(v, s);
  if ((tid & 63) == 0) ws[tid >> 6] = v;
  __syncthreads();
  if (tid == 0) bsum[blockIdx.x] = ws[0] + ws[1] + ws[2] + ws[3];
}

__global__ __launch_bounds__(64) void k_bscan(const int* __restrict__ bsum,
                                              int* __restrict__ boff,
                                              int* __restrict__ off, int NB, int N) {
  int lane = threadIdx.x;
  int carry = 0;
  for (int base = 0; base < NB; base += 64) {
    int i = base + lane;
    int v = (i < NB) ? bsum[i] : 0;
    int sc = v;
    #pragma unroll
    for (int s = 1; s < 64; s <<= 1) {
      int t = __shfl_up(sc, s);
      if (lane >= s) sc += t;
    }
    if (i < NB) boff[i] = carry + sc - v;
    carry += __shfl(sc, 63);
  }
  if (lane == 0) off[N] = carry;
}

__global__ __launch_bounds__(256) void k_scan2(const int* __restrict__ deg,
                                               const int* __restrict__ boff,
                                               int* __restrict__ off,
                                               int* __restrict__ cur, int N) {
  __shared__ int wtot[4];
  int tid = threadIdx.x;
  int lane = tid & 63;
  int base = blockIdx.x * SCH + tid * 4;
  int v[4];
  #pragma unroll
  for (int k = 0; k < 4; k++) v[k] = (base + k < N) ? deg[base + k] : 0;
  int tsum = v[0] + v[1] + v[2] + v[3];
  int sc = tsum;
  #pragma unroll
  for (int s = 1; s < 64; s <<= 1) {
    int t = __shfl_up(sc, s);
    if (lane >= s) sc += t;
  }
  if (lane == 63) wtot[tid >> 6] = sc;
  __syncthreads();
  int w = tid >> 6;
  int woff = 0;
  if (w > 0) woff += wtot[0];
  if (w > 1) woff += wtot[1];
  if (w > 2) woff += wtot[2];
  int pre = boff[blockIdx.x] + woff + sc - tsum;
  #pragma unroll
  for (int k = 0; k < 4; k++) {
    int i = base + k;
    if (i < N) { off[i] = pre; cur[i] = pre; }
    pre += v[k];
  }
}

__global__ void k_scatter(const int* __restrict__ row, const int* __restrict__ col,
                          int* __restrict__ cur, int* __restrict__ csr_row, int E) {
  int e = blockIdx.x * blockDim.x + threadIdx.x;
  if (e < E) {
    int p = atomicAdd(&cur[col[e]], 1);
    csr_row[p] = row[e];
  }
}

// ---------------------------------------------------------------------------
// K6: fused 3-iteration routing + squash + exp_map.  One wave per node.
// u rows (f16) staged once in LDS (8.3 KB/block -> ~2x occupancy vs fp32).
// Round 0 uses exact uniform coefficients (b=0) computed during staging.
// ---------------------------------------------------------------------------
#define CAP 32
__global__ __launch_bounds__(64) void k_route(
    const __half* __restrict__ uh, const float* __restrict__ bias,
    const int* __restrict__ csr_off, const int* __restrict__ csr_row,
    float* __restrict__ bg_ws, float* __restrict__ out, int N) {
  __shared__ __half2 ulds[CAP][64];
  __shared__ float bl[CAP];
  int j = blockIdx.x;
  int lane = threadIdx.x;
  int o0 = csr_off[j];
  int deg = csr_off[j + 1] - o0;
  int d0 = lane * 2;

  if (deg == 0) {
    *(float2*)(out + (size_t)j * 128 + d0) =
        make_float2((lane == 0) ? 1.f : 0.f, 0.f);
    return;
  }

  float2 bia = *(const float2*)(bias + d0);
  float s0 = 0.f, s1 = 0.f;

  if (deg <= CAP) {
    // stage u rows (f16) + accumulate sum for round-0 uniform coefficients
    int myrow = (lane < deg) ? csr_row[o0 + lane] : 0;
    float a0 = 0.f, a1 = 0.f;
    for (int i = 0; i < deg; ++i) {
      int rr = __shfl(myrow, i);
      __half2 hv = ((const __half2*)(uh + ((size_t)rr << 7)))[lane];
      ulds[i][lane] = hv;
      float2 uf = __half22float2(hv);
      a0 += uf.x; a1 += uf.y;
    }
    if (lane < CAP) bl[lane] = 0.f;
    __syncthreads();

    float invd = 1.f / (float)deg;
    s0 = a0 * invd + bia.x;
    s1 = a1 * invd + bia.y;

    for (int r = 0;; ++r) {
      // squash
      float ns = s0 * s0 + s1 * s1;
      #pragma unroll
      for (int s = 32; s; s >>= 1) ns += __shfl_xor(ns, s);
      float scale = (ns / (1.f + ns)) * rsqrtf(ns + 1e-9f);
      s0 *= scale; s1 *= scale;
      if (r == 2) break;

      // b_i += dot(s, u_i): 8 independent butterfly chains per batch
      for (int i0 = 0; i0 < deg; i0 += 8) {
        float p[8];
        #pragma unroll
        for (int k = 0; k < 8; k++) {
          int i = i0 + k;
          float2 u = (i < deg) ? __half22float2(ulds[i][lane])
                               : make_float2(0.f, 0.f);
          p[k] = s0 * u.x + s1 * u.y;
        }
        #pragma unroll
        for (int k = 0; k < 8; k++)
          #pragma unroll
          for (int s = 32; s; s >>= 1) p[k] += __shfl_xor(p[k], s);
        float pv = p[0];
        #pragma unroll
        for (int k = 1; k < 8; k++) pv = (lane == k) ? p[k] : pv;
        if (lane < 8 && i0 + lane < deg) bl[i0 + lane] += pv;
      }
      __syncthreads();

      // softmax-weighted sum (z redundant per lane; no max-shift, |b|<~8)
      float z = 0.f, w0 = 0.f, w1 = 0.f;
      for (int i = 0; i < deg; ++i) {
        float e = __expf(bl[i]);
        float2 u = __half22float2(ulds[i][lane]);
        z += e;
        w0 = fmaf(e, u.x, w0);
        w1 = fmaf(e, u.y, w1);
      }
      float invz = 1.f / z;
      s0 = w0 * invz + bia.x;
      s1 = w1 * invz + bia.y;
    }
  } else {
    // fallback: global-memory b (rare pathological degree)
    float* b = bg_ws + o0;
    for (int i = lane; i < deg; i += 64) b[i] = 0.f;
    __threadfence();
    __syncthreads();

    for (int r = 0; r < 3; ++r) {
      float mx = -3.4e38f;
      for (int i = lane; i < deg; i += 64) mx = fmaxf(mx, b[i]);
      #pragma unroll
      for (int s = 32; s; s >>= 1) mx = fmaxf(mx, __shfl_xor(mx, s));
      float z = 0.f;
      for (int i = lane; i < deg; i += 64) z += expf(b[i] - mx);
      #pragma unroll
      for (int s = 32; s; s >>= 1) z += __shfl_xor(z, s);
      float invz = 1.f / z;

      s0 = 0.f; s1 = 0.f;
      for (int i = 0; i < deg; ++i) {
        float c = expf(b[i] - mx) * invz;
        int rr = csr_row[o0 + i];
        float2 u = __half22float2(((const __half2*)(uh + ((size_t)rr << 7)))[lane]);
        s0 = fmaf(c, u.x, s0);
        s1 = fmaf(c, u.y, s1);
      }
      s0 += bia.x; s1 += bia.y;

      float ns = s0 * s0 + s1 * s1;
      #pragma unroll
      for (int s = 32; s; s >>= 1) ns += __shfl_xor(ns, s);
      float scale = (ns / (1.f + ns)) * rsqrtf(ns + 1e-9f);
      s0 *= scale; s1 *= scale;

      if (r < 2) {
        for (int i = 0; i < deg; ++i) {
          int rr = csr_row[o0 + i];
          float2 u = __half22float2(((const __half2*)(uh + ((size_t)rr << 7)))[lane]);
          float pp = s0 * u.x + s1 * u.y;
          #pragma unroll
          for (int s = 32; s; s >>= 1) pp += __shfl_xor(pp, s);
          if (lane == 0) b[i] += pp;
        }
        __threadfence();
        __syncthreads();
      }
    }
  }

  // exp_map(s, ref)
  float pn = s0 * s0 + s1 * s1;
  if (lane == 0) pn -= 2.f * s0 * s0;
  #pragma unroll
  for (int s = 32; s; s >>= 1) pn += __shfl_xor(pn, s);
  float vn = fminf(sqrtf(fabsf(pn) + 1e-12f), 10.f);
  float sh = sinhf(vn) / vn;
  float ov0 = sh * s0 + ((lane == 0) ? coshf(vn) : 0.f);
  float ov1 = sh * s1;
  *(float2*)(out + (size_t)j * 128 + d0) = make_float2(ov0, ov1);
}

// ---------------------------------------------------------------------------
extern "C" void kernel_launch(void* const* d_in, const int* in_sizes, int n_in,
                              void* d_out, int out_size, void* d_ws, size_t ws_size,
                              hipStream_t stream) {
  const float* x    = (const float*)d_in[0];
  const int*   ei   = (const int*)d_in[1];
  const float* Wp   = (const float*)d_in[2];
  const float* bp   = (const float*)d_in[3];
  const float* Wg   = (const float*)d_in[4];
  const float* bg   = (const float*)d_in[5];
  const float* bias = (const float*)d_in[6];
  float* out = (float*)d_out;

  int N = in_sizes[0] / 128;
  int E = in_sizes[1] / 2;
  const int* row = ei;
  const int* col = ei + E;
  int NB = (N + SCH - 1) / SCH;

  __hip_bfloat16* xtb = (__hip_bfloat16*)d_ws;               // N*128 bf16
  __half* uhh = (__half*)(xtb + (size_t)N * 128);            // N*128 f16
  float* gate = (float*)(uhh + (size_t)N * 128);             // N*4 f32
  __hip_bfloat16* Wt = (__hip_bfloat16*)(gate + (size_t)N * 4); // 512*128 bf16
  float* bws = (float*)(Wt + 512 * 128);                     // E f32
  int* deg = (int*)(bws + E);
  int* off = deg + N;
  int* cur = off + N + 1;
  int* csr_row = cur + N;
  int* bsum = csr_row + E;
  int* boff = bsum + NB;

  hipMemsetAsync(deg, 0, (size_t)N * sizeof(int), stream);
  k_tangent_gate<<<(N + 3) / 4, 256, 0, stream>>>(x, Wg, bg, xtb, gate, N);
  k_wt<<<256, 256, 0, stream>>>(Wp, Wt);
  k_uhat_mfma<<<(N + BM - 1) / BM, 256, 0, stream>>>(
      (const short*)xtb, gate, (const short*)Wt, bp, uhh, N);
  k_hist<<<(E + 255) / 256, 256, 0, stream>>>(col, deg, E);
  k_bsum<<<NB, 256, 0, stream>>>(deg, bsum, N);
  k_bscan<<<1, 64, 0, stream>>>(bsum, boff, off, NB, N);
  k_scan2<<<NB, 256, 0, stream>>>(deg, boff, off, cur, N);
  k_scatter<<<(E + 255) / 256, 256, 0, stream>>>(row, col, cur, csr_row, E);
  k_route<<<N, 64, 0, stream>>>(uhh, bias, off, csr_row, bws, out, N);
}